// Round 1
// baseline (290.426 us; speedup 1.0000x reference)
//
#include <hip/hip_runtime.h>

// Workspace layout (floats)
#define WS_W1Q   0      // 36:   s1*lvl  (exact fp32 values, used by fp64 conv1)
#define WS_W2L   36     // 144:  levels in {-1,0,1}
#define WS_WFL   180    // 1960: levels in {-1,0,1}
#define WS_S2    2140
#define WS_SF    2141

// ---------------------------------------------------------------------------
// Pre-kernel: Brevitas-style 2-bit symmetric weight quantization.
// Decisions (round(w/s)) done in fp64 to match a high-precision reference.
// ---------------------------------------------------------------------------
__global__ void qweights_kernel(const float* __restrict__ w1,
                                const float* __restrict__ w2,
                                const float* __restrict__ wf,
                                float* __restrict__ ws) {
    __shared__ float red[256];
    const int tid = threadIdx.x;

    float m = 0.f;
    for (int i = tid; i < 36; i += 256) m = fmaxf(m, fabsf(w1[i]));
    red[tid] = m; __syncthreads();
    for (int s = 128; s > 0; s >>= 1) { if (tid < s) red[tid] = fmaxf(red[tid], red[tid + s]); __syncthreads(); }
    const float s1 = red[0]; __syncthreads();

    m = 0.f;
    for (int i = tid; i < 144; i += 256) m = fmaxf(m, fabsf(w2[i]));
    red[tid] = m; __syncthreads();
    for (int s = 128; s > 0; s >>= 1) { if (tid < s) red[tid] = fmaxf(red[tid], red[tid + s]); __syncthreads(); }
    const float s2 = red[0]; __syncthreads();

    m = 0.f;
    for (int i = tid; i < 1960; i += 256) m = fmaxf(m, fabsf(wf[i]));
    red[tid] = m; __syncthreads();
    for (int s = 128; s > 0; s >>= 1) { if (tid < s) red[tid] = fmaxf(red[tid], red[tid + s]); __syncthreads(); }
    const float sf = red[0];

    for (int i = tid; i < 36; i += 256) {
        double l = rint((double)w1[i] / (double)s1);
        l = fmin(fmax(l, -1.0), 1.0);
        ws[WS_W1Q + i] = (float)(l * (double)s1);   // exact: s1 * {-1,0,1}
    }
    for (int i = tid; i < 144; i += 256) {
        double l = rint((double)w2[i] / (double)s2);
        l = fmin(fmax(l, -1.0), 1.0);
        ws[WS_W2L + i] = (float)l;
    }
    for (int i = tid; i < 1960; i += 256) {
        double l = rint((double)wf[i] / (double)sf);
        l = fmin(fmax(l, -1.0), 1.0);
        ws[WS_WFL + i] = (float)l;
    }
    if (tid == 0) { ws[WS_S2] = s2; ws[WS_SF] = sf; }
}

// quantized/2 level in {0,1,2,3}; exact-decision fp64
__device__ __forceinline__ double qlevel(double y) {
    return rint(fmin(fmax(y, 0.0), 6.0) * 0.5);
}

// ---------------------------------------------------------------------------
// Fused net: one wave (64 lanes) per image; 4 waves / 256-thread block.
// LDS per wave: padded input 30x30 (900 f), padded pooled1 4x16x16 (1024 f),
// pooled2 196 f  -> ~8.3 KB/wave, ~34 KB/block -> 4 blocks/CU.
// ---------------------------------------------------------------------------
#define WAVES 4
__global__ __launch_bounds__(256, 4)
void fused_net_kernel(const float* __restrict__ x,
                      const float* __restrict__ ws,
                      float* __restrict__ out, int B) {
    __shared__ float s_in[WAVES][900];    // [30][30] zero-padded
    __shared__ float s_p1[WAVES][1024];   // [4][16][16] zero-padded, values {0,2,4,6}
    __shared__ float s_p2[WAVES][196];    // [4][7][7] flat, values {0,2,4,6}

    const int tid  = threadIdx.x;
    const int wave = tid >> 6;
    const int lane = tid & 63;
    const int img  = blockIdx.x * WAVES + wave;
    const bool act = (img < B);

    float* in_p = s_in[wave];
    float* p1   = s_p1[wave];
    float* p2   = s_p2[wave];

    const float* w1q = ws + WS_W1Q;   // s1*lvl
    const float* w2l = ws + WS_W2L;   // levels
    const float* wfl = ws + WS_WFL;   // levels

    // ---- phase 0a: zero padded LDS buffers ----
    for (int t = lane; t < 900; t += 64)  in_p[t] = 0.f;
    for (int t = lane; t < 1024; t += 64) p1[t]   = 0.f;
    __syncthreads();

    // ---- phase 0b: load 28x28 input (float4, coalesced) into padded interior ----
    if (act) {
        const float4* xv = (const float4*)(x + (size_t)img * 784);
        for (int t = lane; t < 196; t += 64) {
            float4 v = xv[t];
            int row = t / 7;
            int c   = (t - row * 7) * 4;
            float* dst = in_p + (row + 1) * 30 + c + 1;
            dst[0] = v.x; dst[1] = v.y; dst[2] = v.z; dst[3] = v.w;
        }
    }
    __syncthreads();

    // ---- phase 1: conv1 (fp64-exact) + quant_relu + 2x2 maxpool -> p1 padded ----
    if (act) {
        for (int t = lane; t < 196; t += 64) {
            int i = t / 14, j = t - i * 14;          // pooled coords, 14x14
            const float* pb = in_p + (2 * i) * 30 + 2 * j;
            double d[16];
            #pragma unroll
            for (int r = 0; r < 4; ++r)
                #pragma unroll
                for (int c = 0; c < 4; ++c)
                    d[r * 4 + c] = (double)pb[r * 30 + c];

            for (int oc = 0; oc < 4; ++oc) {
                double a00 = 0, a01 = 0, a10 = 0, a11 = 0;
                #pragma unroll
                for (int dy = 0; dy < 3; ++dy)
                    #pragma unroll
                    for (int dx = 0; dx < 3; ++dx) {
                        double w = (double)w1q[oc * 9 + dy * 3 + dx];
                        a00 = fma(w, d[dy * 4 + dx],           a00);
                        a01 = fma(w, d[dy * 4 + dx + 1],       a01);
                        a10 = fma(w, d[(dy + 1) * 4 + dx],     a10);
                        a11 = fma(w, d[(dy + 1) * 4 + dx + 1], a11);
                    }
                double q = fmax(fmax(qlevel(a00), qlevel(a01)),
                                fmax(qlevel(a10), qlevel(a11)));
                p1[oc * 256 + (i + 1) * 16 + (j + 1)] = (float)(q * 2.0);
            }
        }
    }
    __syncthreads();

    // ---- phase 2: conv2 (integer-exact fp32) + quant + pool -> p2 ----
    const float s2 = ws[WS_S2];
    if (act) {
        const double s2d = (double)s2;
        for (int t = lane; t < 196; t += 64) {
            int oc = t / 49, rem = t - oc * 49;
            int i = rem / 7, j = rem - i * 7;        // pooled coords, 7x7
            float a00 = 0.f, a01 = 0.f, a10 = 0.f, a11 = 0.f;
            #pragma unroll
            for (int ic = 0; ic < 4; ++ic) {
                const float* pb = p1 + ic * 256 + (2 * i) * 16 + 2 * j;
                float d[16];
                #pragma unroll
                for (int r = 0; r < 4; ++r)
                    #pragma unroll
                    for (int c = 0; c < 4; ++c)
                        d[r * 4 + c] = pb[r * 16 + c];
                #pragma unroll
                for (int dy = 0; dy < 3; ++dy)
                    #pragma unroll
                    for (int dx = 0; dx < 3; ++dx) {
                        float w = w2l[((oc * 4 + ic) * 3 + dy) * 3 + dx];
                        a00 = fmaf(w, d[dy * 4 + dx],           a00);
                        a01 = fmaf(w, d[dy * 4 + dx + 1],       a01);
                        a10 = fmaf(w, d[(dy + 1) * 4 + dx],     a10);
                        a11 = fmaf(w, d[(dy + 1) * 4 + dx + 1], a11);
                    }
            }
            // pre-activations are exactly s2 * K (K even integer, |K|<=216)
            double q = fmax(fmax(qlevel((double)a00 * s2d), qlevel((double)a01 * s2d)),
                            fmax(qlevel((double)a10 * s2d), qlevel((double)a11 * s2d)));
            p2[t] = (float)(q * 2.0);                // {0,2,4,6}, flatten order c*49+i*7+j
        }
    }
    __syncthreads();

    // ---- phase 3: FC (integer-exact) + wave reduction ----
    if (act) {
        float acc[10];
        #pragma unroll
        for (int o = 0; o < 10; ++o) acc[o] = 0.f;
        for (int k = lane; k < 196; k += 64) {
            float h = p2[k];
            #pragma unroll
            for (int o = 0; o < 10; ++o)
                acc[o] = fmaf(h, wfl[o * 196 + k], acc[o]);
        }
        #pragma unroll
        for (int o = 0; o < 10; ++o) {
            #pragma unroll
            for (int off = 32; off > 0; off >>= 1)
                acc[o] += __shfl_xor(acc[o], off, 64);
        }
        if (lane == 0) {
            const float sf = ws[WS_SF];
            float* op = out + (size_t)img * 10;
            #pragma unroll
            for (int o = 0; o < 10; ++o) op[o] = sf * acc[o];
        }
    }
}

extern "C" void kernel_launch(void* const* d_in, const int* in_sizes, int n_in,
                              void* d_out, int out_size, void* d_ws, size_t ws_size,
                              hipStream_t stream) {
    const float* x  = (const float*)d_in[0];
    const float* w1 = (const float*)d_in[1];
    const float* w2 = (const float*)d_in[2];
    const float* wf = (const float*)d_in[3];
    float* ws  = (float*)d_ws;
    float* out = (float*)d_out;

    const int B = in_sizes[0] / 784;

    qweights_kernel<<<1, 256, 0, stream>>>(w1, w2, wf, ws);
    fused_net_kernel<<<(B + WAVES - 1) / WAVES, 256, 0, stream>>>(x, ws, out, B);
}

// Round 2
// 247.795 us; speedup vs baseline: 1.1720x; 1.1720x over previous
//
#include <hip/hip_runtime.h>

// Workspace layout (floats)
#define WS_W1Q   0      // 36:   s1*lvl (exact fp32 = s1 * {-1,0,1})
#define WS_W2L   36     // 144:  conv2 levels in {-1,0,1}
#define WS_WFT   180    // 2352: FC levels transposed+padded [196][12]
#define WS_T1    2532   // conv2 integer thresholds (K1-0.5 etc.)
#define WS_T3    2533
#define WS_T5    2534
#define WS_SF    2535

#define TOL 1e-4f

// ---------------------------------------------------------------------------
// Pre-kernel: 2-bit symmetric weight quant; decisions in fp64.
// Also: conv2 integer decision thresholds, FC weight transpose.
// ---------------------------------------------------------------------------
__global__ void qweights_kernel(const float* __restrict__ w1,
                                const float* __restrict__ w2,
                                const float* __restrict__ wf,
                                float* __restrict__ ws) {
    __shared__ float red[256];
    const int tid = threadIdx.x;

    float m = 0.f;
    for (int i = tid; i < 36; i += 256) m = fmaxf(m, fabsf(w1[i]));
    red[tid] = m; __syncthreads();
    for (int s = 128; s > 0; s >>= 1) { if (tid < s) red[tid] = fmaxf(red[tid], red[tid + s]); __syncthreads(); }
    const float s1 = red[0]; __syncthreads();

    m = 0.f;
    for (int i = tid; i < 144; i += 256) m = fmaxf(m, fabsf(w2[i]));
    red[tid] = m; __syncthreads();
    for (int s = 128; s > 0; s >>= 1) { if (tid < s) red[tid] = fmaxf(red[tid], red[tid + s]); __syncthreads(); }
    const float s2 = red[0]; __syncthreads();

    m = 0.f;
    for (int i = tid; i < 1960; i += 256) m = fmaxf(m, fabsf(wf[i]));
    red[tid] = m; __syncthreads();
    for (int s = 128; s > 0; s >>= 1) { if (tid < s) red[tid] = fmaxf(red[tid], red[tid + s]); __syncthreads(); }
    const float sf = red[0]; __syncthreads();

    for (int i = tid; i < 36; i += 256) {
        double l = rint((double)w1[i] / (double)s1);
        l = fmin(fmax(l, -1.0), 1.0);
        ws[WS_W1Q + i] = (float)(l * (double)s1);
    }
    for (int i = tid; i < 144; i += 256) {
        double l = rint((double)w2[i] / (double)s2);
        l = fmin(fmax(l, -1.0), 1.0);
        ws[WS_W2L + i] = (float)l;
    }
    // FC transpose: wft[k][o] (pitch 12), zero-padded
    for (int i = tid; i < 2352; i += 256) ws[WS_WFT + i] = 0.f;
    __syncthreads();
    for (int i = tid; i < 1960; i += 256) {
        int o = i / 196, k = i - o * 196;
        double l = rint((double)wf[i] / (double)sf);
        l = fmin(fmax(l, -1.0), 1.0);
        ws[WS_WFT + k * 12 + o] = (float)l;
    }
    if (tid == 0) {
        // conv2 pre-acts are exactly s2*K (K even int, 0<=|K|<=216).
        // level(K) = rint(min(max(s2*K,0),6)/2), exact in fp64. Monotone in K.
        int K1 = 10000, K3 = 10000, K5 = 10000;
        for (int K = 216; K >= 0; --K) {
            double xv = (double)s2 * (double)K;
            double lv = rint(fmin(fmax(xv, 0.0), 6.0) * 0.5);
            if (lv >= 1.0) K1 = K;
            if (lv >= 2.0) K3 = K;
            if (lv >= 3.0) K5 = K;
        }
        ws[WS_T1] = (float)K1 - 0.5f;
        ws[WS_T3] = (float)K3 - 0.5f;
        ws[WS_T5] = (float)K5 - 0.5f;
        ws[WS_SF] = sf;
    }
}

// ---------------------------------------------------------------------------
// Fused net: one wave per image, 4 waves/block.
// LDS/wave: in 30x30 (900f), p1 4x16x18 (1152f), p2 200f -> 36KB/block.
// ---------------------------------------------------------------------------
#define WAVES 4
#define P_IN 30
#define P_P1 18
#define IC_STRIDE (16 * P_P1)   // 288

__global__ __launch_bounds__(256, 4)
void fused_net_kernel(const float* __restrict__ x,
                      const float* __restrict__ ws,
                      float* __restrict__ out, int B) {
    __shared__ __align__(16) float s_in[WAVES][900];
    __shared__ __align__(16) float s_p1[WAVES][4 * IC_STRIDE];
    __shared__ __align__(16) float s_p2[WAVES][200];

    const int tid  = threadIdx.x;
    const int wave = tid >> 6;
    const int lane = tid & 63;
    const int img  = blockIdx.x * WAVES + wave;
    const bool act = (img < B);

    float* in_p = s_in[wave];
    float* p1   = s_p1[wave];
    float* p2   = s_p2[wave];

    const float* w1 = ws + WS_W1Q;
    const float* w2 = ws + WS_W2L;

    // ---- phase 0a: zero padded buffers (float4) ----
    {
        float4 z = make_float4(0.f, 0.f, 0.f, 0.f);
        float4* z1 = (float4*)in_p;
        for (int t = lane; t < 225; t += 64) z1[t] = z;
        float4* z2 = (float4*)p1;
        for (int t = lane; t < 288; t += 64) z2[t] = z;
    }
    __syncthreads();

    // ---- phase 0b: load 28x28 input into padded interior ----
    if (act) {
        const float4* xv = (const float4*)(x + (size_t)img * 784);
        for (int t = lane; t < 196; t += 64) {
            float4 v = xv[t];
            int row = t / 7;
            int c   = (t - row * 7) * 4;
            float* dst = in_p + (row + 1) * P_IN + c + 1;
            dst[0] = v.x; dst[1] = v.y; dst[2] = v.z; dst[3] = v.w;
        }
    }
    __syncthreads();

    // ---- phase 1: conv1 fp32 (+fp64 rescue) + pool-then-quant ----
    if (act) {
        for (int t = lane; t < 196; t += 64) {
            int i = t / 14, j = t - i * 14;           // pooled coords 14x14
            const float* base = in_p + (2 * i) * P_IN + 2 * j;
            float d[4][4];
            #pragma unroll
            for (int r = 0; r < 4; ++r) {
                const float* rp = base + r * P_IN;    // 8B aligned
                float2 a = *(const float2*)rp;
                float2 b = *(const float2*)(rp + 2);
                d[r][0] = a.x; d[r][1] = a.y; d[r][2] = b.x; d[r][3] = b.y;
            }

            float lvlv[4];
            float chkmin = 1e9f;
            #pragma unroll
            for (int oc = 0; oc < 4; ++oc) {
                float a00 = 0.f, a01 = 0.f, a10 = 0.f, a11 = 0.f;
                #pragma unroll
                for (int r = 0; r < 3; ++r)
                    #pragma unroll
                    for (int c = 0; c < 3; ++c) {
                        float wv = w1[oc * 9 + r * 3 + c];
                        a00 = fmaf(wv, d[r][c],         a00);
                        a01 = fmaf(wv, d[r][c + 1],     a01);
                        a10 = fmaf(wv, d[r + 1][c],     a10);
                        a11 = fmaf(wv, d[r + 1][c + 1], a11);
                    }
                float mx = fmaxf(fmaxf(a00, a01), fmaxf(a10, a11));
                lvlv[oc] = rintf(fminf(fmaxf(mx, 0.f), 6.f) * 0.5f);
                // distance to nearest boundary {1,3,5}
                float d3 = fabsf(mx - 3.f);
                chkmin = fminf(chkmin, fminf(d3, fabsf(d3 - 2.f)));
            }
            if (chkmin < TOL) {                        // rare fp64 rescue
                double dd[4][4];
                #pragma unroll
                for (int r = 0; r < 4; ++r)
                    #pragma unroll
                    for (int c = 0; c < 4; ++c) dd[r][c] = (double)d[r][c];
                #pragma unroll
                for (int oc = 0; oc < 4; ++oc) {
                    double a00 = 0, a01 = 0, a10 = 0, a11 = 0;
                    #pragma unroll
                    for (int r = 0; r < 3; ++r)
                        #pragma unroll
                        for (int c = 0; c < 3; ++c) {
                            double wv = (double)w1[oc * 9 + r * 3 + c];
                            a00 = fma(wv, dd[r][c],         a00);
                            a01 = fma(wv, dd[r][c + 1],     a01);
                            a10 = fma(wv, dd[r + 1][c],     a10);
                            a11 = fma(wv, dd[r + 1][c + 1], a11);
                        }
                    double mx = fmax(fmax(a00, a01), fmax(a10, a11));
                    lvlv[oc] = (float)rint(fmin(fmax(mx, 0.0), 6.0) * 0.5);
                }
            }
            #pragma unroll
            for (int oc = 0; oc < 4; ++oc)
                p1[oc * IC_STRIDE + (i + 1) * P_P1 + (j + 1)] = 2.f * lvlv[oc];
        }
    }
    __syncthreads();

    // ---- phase 2: conv2 integer-exact fp32 + pool + threshold quant ----
    if (act && lane < 49) {
        const float t1 = ws[WS_T1], t3 = ws[WS_T3], t5 = ws[WS_T5];
        int i = lane / 7, j = lane - 7 * i;           // pooled coords 7x7
        float acc[4][4];
        #pragma unroll
        for (int oc = 0; oc < 4; ++oc)
            #pragma unroll
            for (int p = 0; p < 4; ++p) acc[oc][p] = 0.f;

        #pragma unroll
        for (int ic = 0; ic < 4; ++ic) {
            const float* bp = p1 + ic * IC_STRIDE + (2 * i) * P_P1 + 2 * j;
            float d[4][4];
            #pragma unroll
            for (int r = 0; r < 4; ++r) {
                const float* rp = bp + r * P_P1;      // 8B aligned
                float2 a = *(const float2*)rp;
                float2 b = *(const float2*)(rp + 2);
                d[r][0] = a.x; d[r][1] = a.y; d[r][2] = b.x; d[r][3] = b.y;
            }
            #pragma unroll
            for (int oc = 0; oc < 4; ++oc)
                #pragma unroll
                for (int r = 0; r < 3; ++r)
                    #pragma unroll
                    for (int c = 0; c < 3; ++c) {
                        float wv = w2[(oc * 4 + ic) * 9 + r * 3 + c];
                        acc[oc][0] = fmaf(wv, d[r][c],         acc[oc][0]);
                        acc[oc][1] = fmaf(wv, d[r][c + 1],     acc[oc][1]);
                        acc[oc][2] = fmaf(wv, d[r + 1][c],     acc[oc][2]);
                        acc[oc][3] = fmaf(wv, d[r + 1][c + 1], acc[oc][3]);
                    }
        }
        #pragma unroll
        for (int oc = 0; oc < 4; ++oc) {
            float mx = fmaxf(fmaxf(acc[oc][0], acc[oc][1]),
                             fmaxf(acc[oc][2], acc[oc][3]));
            float lv = (mx > t1 ? 1.f : 0.f) + (mx > t3 ? 1.f : 0.f)
                     + (mx > t5 ? 1.f : 0.f);
            p2[oc * 49 + lane] = 2.f * lv;
        }
    }
    __syncthreads();

    // ---- phase 3: FC (integer-exact) + wave butterfly reduction ----
    if (act) {
        float acc[10];
        #pragma unroll
        for (int o = 0; o < 10; ++o) acc[o] = 0.f;
        for (int k = lane; k < 196; k += 64) {
            float h = p2[k];
            const float4* wr = (const float4*)(ws + WS_WFT + k * 12);
            float4 a = wr[0], b = wr[1], c = wr[2];
            acc[0] = fmaf(h, a.x, acc[0]); acc[1] = fmaf(h, a.y, acc[1]);
            acc[2] = fmaf(h, a.z, acc[2]); acc[3] = fmaf(h, a.w, acc[3]);
            acc[4] = fmaf(h, b.x, acc[4]); acc[5] = fmaf(h, b.y, acc[5]);
            acc[6] = fmaf(h, b.z, acc[6]); acc[7] = fmaf(h, b.w, acc[7]);
            acc[8] = fmaf(h, c.x, acc[8]); acc[9] = fmaf(h, c.y, acc[9]);
        }
        #pragma unroll
        for (int o = 0; o < 10; ++o) {
            #pragma unroll
            for (int off = 32; off > 0; off >>= 1)
                acc[o] += __shfl_xor(acc[o], off, 64);
        }
        if (lane == 0) {
            const float sf = ws[WS_SF];
            float2* op = (float2*)(out + (size_t)img * 10);
            #pragma unroll
            for (int o = 0; o < 5; ++o)
                op[o] = make_float2(sf * acc[2 * o], sf * acc[2 * o + 1]);
        }
    }
}

extern "C" void kernel_launch(void* const* d_in, const int* in_sizes, int n_in,
                              void* d_out, int out_size, void* d_ws, size_t ws_size,
                              hipStream_t stream) {
    const float* x  = (const float*)d_in[0];
    const float* w1 = (const float*)d_in[1];
    const float* w2 = (const float*)d_in[2];
    const float* wf = (const float*)d_in[3];
    float* ws  = (float*)d_ws;
    float* out = (float*)d_out;

    const int B = in_sizes[0] / 784;

    qweights_kernel<<<1, 256, 0, stream>>>(w1, w2, wf, ws);
    fused_net_kernel<<<(B + WAVES - 1) / WAVES, 256, 0, stream>>>(x, ws, out, B);
}

// Round 3
// 210.066 us; speedup vs baseline: 1.3825x; 1.1796x over previous
//
#include <hip/hip_runtime.h>

// Workspace layout: float region + int region (starts at float index 64)
#define WSF_W1Q  0      // 36 floats: s1*lvl (exact)
#define WSF_SF2  36     // 2*sf
#define WSI_W2P  0      // 36 ints: conv2 packed ternary i8x4 (ic in bytes), [oc][tap]
#define WSI_L1   36     // conv2 integer thresholds on L = sum(lvl_in * w)
#define WSI_L3   37
#define WSI_L5   38
#define WSI_WFP  40     // 64*12 ints: FC packed ternary i8x4 (k in bytes), [k4][o] pitch 12

#define TOL 1e-4f

__device__ __forceinline__ int dot4(int a, int b, int c) {
#if __has_builtin(__builtin_amdgcn_sdot4)
    return __builtin_amdgcn_sdot4(a, b, c, false);
#else
    c += (int)(signed char)(a)       * (int)(signed char)(b);
    c += (int)(signed char)(a >> 8)  * (int)(signed char)(b >> 8);
    c += (int)(signed char)(a >> 16) * (int)(signed char)(b >> 16);
    c += (int)(signed char)(a >> 24) * (int)(signed char)(b >> 24);
    return c;
#endif
}

// ---------------------------------------------------------------------------
// Pre-kernel: 2-bit weight quant (fp64 decisions) + integer packing.
// ---------------------------------------------------------------------------
__global__ void qweights_kernel(const float* __restrict__ w1,
                                const float* __restrict__ w2,
                                const float* __restrict__ wf,
                                float* __restrict__ wsf) {
    int* wsi = (int*)wsf + 64;
    __shared__ float red[256];
    const int tid = threadIdx.x;

    float m = 0.f;
    for (int i = tid; i < 36; i += 256) m = fmaxf(m, fabsf(w1[i]));
    red[tid] = m; __syncthreads();
    for (int s = 128; s > 0; s >>= 1) { if (tid < s) red[tid] = fmaxf(red[tid], red[tid + s]); __syncthreads(); }
    const float s1 = red[0]; __syncthreads();

    m = 0.f;
    for (int i = tid; i < 144; i += 256) m = fmaxf(m, fabsf(w2[i]));
    red[tid] = m; __syncthreads();
    for (int s = 128; s > 0; s >>= 1) { if (tid < s) red[tid] = fmaxf(red[tid], red[tid + s]); __syncthreads(); }
    const float s2 = red[0]; __syncthreads();

    m = 0.f;
    for (int i = tid; i < 1960; i += 256) m = fmaxf(m, fabsf(wf[i]));
    red[tid] = m; __syncthreads();
    for (int s = 128; s > 0; s >>= 1) { if (tid < s) red[tid] = fmaxf(red[tid], red[tid + s]); __syncthreads(); }
    const float sf = red[0];

    for (int i = tid; i < 36; i += 256) {
        double l = rint((double)w1[i] / (double)s1);
        l = fmin(fmax(l, -1.0), 1.0);
        wsf[WSF_W1Q + i] = (float)(l * (double)s1);
    }
    // conv2 packed: wsi[oc*9 + tap], byte ic = level of w2[((oc*4+ic)*3+dy)*3+dx]
    for (int u = tid; u < 36; u += 256) {
        int oc = u / 9, tap = u - oc * 9;
        int dy = tap / 3, dx = tap - dy * 3;
        int v = 0;
        for (int ic = 0; ic < 4; ++ic) {
            double l = rint((double)w2[((oc * 4 + ic) * 3 + dy) * 3 + dx] / (double)s2);
            l = fmin(fmax(l, -1.0), 1.0);
            v |= ((int)l & 0xFF) << (8 * ic);
        }
        wsi[WSI_W2P + u] = v;
    }
    // FC packed: wsi[WFP + k4*12 + o], byte b = level of wf[o*196 + 4*k4+b]
    for (int u = tid; u < 64 * 12; u += 256) {
        int k4 = u / 12, o = u - k4 * 12;
        int v = 0;
        if (o < 10) {
            for (int b = 0; b < 4; ++b) {
                int k = 4 * k4 + b;
                if (k < 196) {
                    double l = rint((double)wf[o * 196 + k] / (double)sf);
                    l = fmin(fmax(l, -1.0), 1.0);
                    v |= ((int)l & 0xFF) << (8 * b);
                }
            }
        }
        wsi[WSI_WFP + u] = v;
    }
    if (tid == 0) {
        // conv2 pre-act = s2 * 2 * L (L = sum of lvl{0..3} * w{-1,0,1}, |L|<=108)
        int L1 = 10000, L3 = 10000, L5 = 10000;
        for (int L = 108; L >= 0; --L) {
            double xv = 2.0 * (double)s2 * (double)L;
            double lv = rint(fmin(fmax(xv, 0.0), 6.0) * 0.5);
            if (lv >= 1.0) L1 = L;
            if (lv >= 2.0) L3 = L;
            if (lv >= 3.0) L5 = L;
        }
        wsi[WSI_L1] = L1; wsi[WSI_L3] = L3; wsi[WSI_L5] = L5;
        wsf[WSF_SF2] = 2.0f * sf;
    }
}

// ---------------------------------------------------------------------------
// Fused net: one wave per image, 4 waves/block, ~20KB LDS -> 8 blocks/CU.
// ---------------------------------------------------------------------------
#define WAVES 4
#define P_IN 30
#define P_P1 18   // pooled1 packed-int pitch (16 rows x 18)

__global__ __launch_bounds__(256, 8)
void fused_net_kernel(const float* __restrict__ x,
                      const float* __restrict__ wsf,
                      float* __restrict__ out, int B) {
    const int* wsi = (const int*)wsf + 64;

    __shared__ __align__(16) float s_in[WAVES][900];          // 30x30 padded
    __shared__ __align__(16) int   s_p1[WAVES][16 * P_P1];    // packed {0..3} x4 ic
    __shared__ __align__(16) unsigned char s_p2[WAVES][256];  // 196 level bytes

    const int tid  = threadIdx.x;
    const int wave = tid >> 6;
    const int lane = tid & 63;
    const int img  = blockIdx.x * WAVES + wave;
    const bool act = (img < B);

    float* in_p = s_in[wave];
    int*   p1i  = s_p1[wave];
    unsigned char* p2b = s_p2[wave];

    const float* w1 = wsf + WSF_W1Q;

    // ---- phase 0a: zero padded buffers ----
    {
        float4 zf = make_float4(0.f, 0.f, 0.f, 0.f);
        float4* z1 = (float4*)in_p;
        for (int t = lane; t < 225; t += 64) z1[t] = zf;
        int4 zi = make_int4(0, 0, 0, 0);
        int4* z2 = (int4*)p1i;
        for (int t = lane; t < 72; t += 64) z2[t] = zi;
    }
    __syncthreads();

    // ---- phase 0b: load 28x28 input into padded interior ----
    if (act) {
        const float4* xv = (const float4*)(x + (size_t)img * 784);
        for (int t = lane; t < 196; t += 64) {
            float4 v = xv[t];
            int row = t / 7;
            int c   = (t - row * 7) * 4;
            float* dst = in_p + (row + 1) * P_IN + c + 1;
            dst[0] = v.x; dst[1] = v.y; dst[2] = v.z; dst[3] = v.w;
        }
    }
    __syncthreads();

    // ---- phase 1: conv1 fp32 (+fp64 rescue) + pool + quant -> packed ints ----
    if (act) {
        for (int t = lane; t < 196; t += 64) {
            int i = t / 14, j = t - i * 14;           // pooled coords 14x14
            const float* base = in_p + (2 * i) * P_IN + 2 * j;
            float d[4][4];
            #pragma unroll
            for (int r = 0; r < 4; ++r) {
                const float* rp = base + r * P_IN;
                float2 a = *(const float2*)rp;
                float2 b = *(const float2*)(rp + 2);
                d[r][0] = a.x; d[r][1] = a.y; d[r][2] = b.x; d[r][3] = b.y;
            }

            int lv[4];
            float chkmin = 1e9f;
            #pragma unroll
            for (int oc = 0; oc < 4; ++oc) {
                float a00 = 0.f, a01 = 0.f, a10 = 0.f, a11 = 0.f;
                #pragma unroll
                for (int r = 0; r < 3; ++r)
                    #pragma unroll
                    for (int c = 0; c < 3; ++c) {
                        float wv = w1[oc * 9 + r * 3 + c];
                        a00 = fmaf(wv, d[r][c],         a00);
                        a01 = fmaf(wv, d[r][c + 1],     a01);
                        a10 = fmaf(wv, d[r + 1][c],     a10);
                        a11 = fmaf(wv, d[r + 1][c + 1], a11);
                    }
                float mx = fmaxf(fmaxf(a00, a01), fmaxf(a10, a11));
                lv[oc] = (mx > 1.f) + (mx > 3.f) + (mx > 5.f);
                float d3 = fabsf(mx - 3.f);
                chkmin = fminf(chkmin, fminf(d3, fabsf(d3 - 2.f)));
            }
            if (chkmin < TOL) {                        // rare fp64 rescue
                double dd[4][4];
                #pragma unroll
                for (int r = 0; r < 4; ++r)
                    #pragma unroll
                    for (int c = 0; c < 4; ++c) dd[r][c] = (double)d[r][c];
                #pragma unroll
                for (int oc = 0; oc < 4; ++oc) {
                    double a00 = 0, a01 = 0, a10 = 0, a11 = 0;
                    #pragma unroll
                    for (int r = 0; r < 3; ++r)
                        #pragma unroll
                        for (int c = 0; c < 3; ++c) {
                            double wv = (double)w1[oc * 9 + r * 3 + c];
                            a00 = fma(wv, dd[r][c],         a00);
                            a01 = fma(wv, dd[r][c + 1],     a01);
                            a10 = fma(wv, dd[r + 1][c],     a10);
                            a11 = fma(wv, dd[r + 1][c + 1], a11);
                        }
                    double mx = fmax(fmax(a00, a01), fmax(a10, a11));
                    lv[oc] = (int)rint(fmin(fmax(mx, 0.0), 6.0) * 0.5);
                }
            }
            p1i[(i + 1) * P_P1 + (j + 1)] =
                lv[0] | (lv[1] << 8) | (lv[2] << 16) | (lv[3] << 24);
        }
    }
    __syncthreads();

    // ---- phase 2: conv2 via sdot4 + pool + integer-threshold quant ----
    if (act) {
        const int ocl = lane & 3;                     // loop-invariant
        int w2r[9];
        #pragma unroll
        for (int t = 0; t < 9; ++t) w2r[t] = wsi[WSI_W2P + ocl * 9 + t];
        const int L1 = wsi[WSI_L1], L3 = wsi[WSI_L3], L5 = wsi[WSI_L5];

        for (int u = lane; u < 196; u += 64) {
            int pix = u >> 2;                         // 0..48, quad-shared
            int i = pix / 7, j = pix - 7 * i;
            const int* bp = p1i + (2 * i) * P_P1 + 2 * j;
            int d[4][4];
            #pragma unroll
            for (int r = 0; r < 4; ++r) {
                int2 a = *(const int2*)(bp + r * P_P1);
                int2 b = *(const int2*)(bp + r * P_P1 + 2);
                d[r][0] = a.x; d[r][1] = a.y; d[r][2] = b.x; d[r][3] = b.y;
            }
            int a00 = 0, a01 = 0, a10 = 0, a11 = 0;
            #pragma unroll
            for (int r = 0; r < 3; ++r)
                #pragma unroll
                for (int c = 0; c < 3; ++c) {
                    int wv = w2r[r * 3 + c];
                    a00 = dot4(d[r][c],         wv, a00);
                    a01 = dot4(d[r][c + 1],     wv, a01);
                    a10 = dot4(d[r + 1][c],     wv, a10);
                    a11 = dot4(d[r + 1][c + 1], wv, a11);
                }
            int mx = max(max(a00, a01), max(a10, a11));
            int lvq = (mx >= L1) + (mx >= L3) + (mx >= L5);
            p2b[ocl * 49 + pix] = (unsigned char)lvq;
        }
    }
    __syncthreads();

    // ---- phase 3: FC via sdot4 + integer butterfly reduce ----
    if (act) {
        int acc[10];
        #pragma unroll
        for (int o = 0; o < 10; ++o) acc[o] = 0;
        if (lane < 49) {
            int h4 = ((const int*)p2b)[lane];
            const int* wr = wsi + WSI_WFP + lane * 12;
            #pragma unroll
            for (int o = 0; o < 10; ++o) acc[o] = dot4(h4, wr[o], acc[o]);
        }
        #pragma unroll
        for (int o = 0; o < 10; ++o) {
            #pragma unroll
            for (int off = 32; off > 0; off >>= 1)
                acc[o] += __shfl_xor(acc[o], off, 64);
        }
        if (lane == 0) {
            const float sf2 = wsf[WSF_SF2];
            float2* op = (float2*)(out + (size_t)img * 10);
            #pragma unroll
            for (int o = 0; o < 5; ++o)
                op[o] = make_float2(sf2 * (float)acc[2 * o],
                                    sf2 * (float)acc[2 * o + 1]);
        }
    }
}

extern "C" void kernel_launch(void* const* d_in, const int* in_sizes, int n_in,
                              void* d_out, int out_size, void* d_ws, size_t ws_size,
                              hipStream_t stream) {
    const float* x  = (const float*)d_in[0];
    const float* w1 = (const float*)d_in[1];
    const float* w2 = (const float*)d_in[2];
    const float* wf = (const float*)d_in[3];
    float* wsf = (float*)d_ws;
    float* out = (float*)d_out;

    const int B = in_sizes[0] / 784;

    qweights_kernel<<<1, 256, 0, stream>>>(w1, w2, wf, wsf);
    fused_net_kernel<<<(B + WAVES - 1) / WAVES, 256, 0, stream>>>(x, wsf, out, B);
}

// Round 4
// 197.788 us; speedup vs baseline: 1.4684x; 1.0621x over previous
//
#include <hip/hip_runtime.h>

// Workspace layout: float region + int region (ints start at (int*)wsf + 64)
#define WSF_W1Q  0      // 36 floats: s1*lvl (exact)
#define WSF_SF2  36     // 2*sf
#define WSI_W2P  0      // 36 ints: conv2 packed ternary i8x4 (ic in bytes), [oc][tap]
#define WSI_L1   36     // conv2 integer thresholds on L = sum(lvl_in * w), lvl in {0..3}
#define WSI_L3   37
#define WSI_L5   38
#define WSI_WFP  40     // 49*12 ints: FC packed ternary i8x4, [pix][o] pitch 12; byte b = wf[o][b*49+pix]

#define TOL2 4e-5f      // rescue band half-width in f-units (f = mx/2)

__device__ __forceinline__ int dot4(int a, int b, int c) {
    return __builtin_amdgcn_sdot4(a, b, c, false);
}

__device__ __forceinline__ int pk_add16(int a, int b) {
    int r;
    asm("v_pk_add_i16 %0, %1, %2" : "=v"(r) : "v"(a), "v"(b));
    return r;
}

// wave-local LDS drain: guarantees prior DS writes are visible to this wave's
// later DS reads, without a cross-wave __syncthreads rendezvous.
#define LDS_FENCE() asm volatile("s_waitcnt lgkmcnt(0)" ::: "memory")

// ---------------------------------------------------------------------------
// Pre-kernel: 2-bit weight quant (fp64 decisions) + integer packing.
// Single wave of 64, shuffle reductions, ballot-derived thresholds.
// ---------------------------------------------------------------------------
__global__ void qweights_kernel(const float* __restrict__ w1,
                                const float* __restrict__ w2,
                                const float* __restrict__ wf,
                                float* __restrict__ wsf) {
    int* wsi = (int*)wsf + 64;
    const int lane = threadIdx.x;

    float m1 = 0.f, m2 = 0.f, mf = 0.f;
    if (lane < 36) m1 = fabsf(w1[lane]);
    for (int i = lane; i < 144; i += 64)  m2 = fmaxf(m2, fabsf(w2[i]));
    for (int i = lane; i < 1960; i += 64) mf = fmaxf(mf, fabsf(wf[i]));
    #pragma unroll
    for (int off = 32; off; off >>= 1) {
        m1 = fmaxf(m1, __shfl_xor(m1, off, 64));
        m2 = fmaxf(m2, __shfl_xor(m2, off, 64));
        mf = fmaxf(mf, __shfl_xor(mf, off, 64));
    }
    const float s1 = m1, s2 = m2, sf = mf;

    if (lane < 36) {
        double l = rint((double)w1[lane] / (double)s1);
        l = fmin(fmax(l, -1.0), 1.0);
        wsf[WSF_W1Q + lane] = (float)(l * (double)s1);
    }
    if (lane < 36) {
        int oc = lane / 9, tap = lane % 9;
        int dy = tap / 3, dx = tap % 3;
        int v = 0;
        for (int ic = 0; ic < 4; ++ic) {
            double l = rint((double)w2[((oc * 4 + ic) * 3 + dy) * 3 + dx] / (double)s2);
            l = fmin(fmax(l, -1.0), 1.0);
            v |= ((int)l & 0xFF) << (8 * ic);
        }
        wsi[WSI_W2P + lane] = v;
    }
    // FC pack [pix][o]: byte b = lvl(wf[o*196 + b*49 + pix]) -- matches p2 packing
    for (int u = lane; u < 49 * 12; u += 64) {
        int pix = u / 12, o = u - 12 * pix;
        int v = 0;
        if (o < 10) {
            for (int b = 0; b < 4; ++b) {
                double l = rint((double)wf[o * 196 + b * 49 + pix] / (double)sf);
                l = fmin(fmax(l, -1.0), 1.0);
                v |= ((int)l & 0xFF) << (8 * b);
            }
        }
        wsi[WSI_WFP + u] = v;
    }
    // conv2 thresholds: pre-act = 2*s2*L, L = sum(lvl{0..3}*w{-1,0,1}), |L|<=108.
    // lvl_out(L) = rint(min(max(2*s2*L,0),6)/2); monotone in L -> ballot+ffs.
    {
        double xa = 2.0 * (double)s2 * (double)lane;
        double xb = 2.0 * (double)s2 * (double)(lane + 64);
        double la = rint(fmin(fmax(xa, 0.0), 6.0) * 0.5);
        double lb = rint(fmin(fmax(xb, 0.0), 6.0) * 0.5);
        unsigned long long b1a = __ballot(la >= 1.0), b1b = __ballot(lb >= 1.0);
        unsigned long long b3a = __ballot(la >= 2.0), b3b = __ballot(lb >= 2.0);
        unsigned long long b5a = __ballot(la >= 3.0), b5b = __ballot(lb >= 3.0);
        if (lane == 0) {
            int L1 = b1a ? __ffsll(b1a) - 1 : (b1b ? 64 + __ffsll(b1b) - 1 : 4096);
            int L3 = b3a ? __ffsll(b3a) - 1 : (b3b ? 64 + __ffsll(b3b) - 1 : 4096);
            int L5 = b5a ? __ffsll(b5a) - 1 : (b5b ? 64 + __ffsll(b5b) - 1 : 4096);
            wsi[WSI_L1] = L1; wsi[WSI_L3] = L3; wsi[WSI_L5] = L5;
            wsf[WSF_SF2] = 2.0f * sf;
        }
    }
}

// ---------------------------------------------------------------------------
// Fused net: one wave per image, 4 waves/block, zero inter-wave LDS sharing
// -> no __syncthreads, only per-wave lgkmcnt fences. ~19.4KB LDS -> 8 blk/CU.
// ---------------------------------------------------------------------------
#define WAVES 4
#define P_IN 30
#define P_P1 18

__global__ __launch_bounds__(256, 8)
void fused_net_kernel(const float* __restrict__ x,
                      const float* __restrict__ wsf,
                      float* __restrict__ out, int B) {
    const int* wsi = (const int*)wsf + 64;

    __shared__ __align__(16) float s_in[WAVES][900];        // 30x30 padded
    __shared__ __align__(16) int   s_p1[WAVES][16 * P_P1];  // packed lvl{0..3} x4 ic
    __shared__ __align__(16) int   s_p2[WAVES][52];         // [pix] packed 4 oc levels

    const int tid  = threadIdx.x;
    const int wave = tid >> 6;
    const int lane = tid & 63;
    const int img  = blockIdx.x * WAVES + wave;
    const bool act = (img < B);

    float* in_p = s_in[wave];
    int*   p1i  = s_p1[wave];
    int*   p2i  = s_p2[wave];
    const float* w1 = wsf + WSF_W1Q;

    // ---- phase 0a: zero padded buffers ----
    {
        float4 zf = make_float4(0.f, 0.f, 0.f, 0.f);
        float4* z1 = (float4*)in_p;
        for (int t = lane; t < 225; t += 64) z1[t] = zf;
        int4 zi = make_int4(0, 0, 0, 0);
        int4* z2 = (int4*)p1i;
        for (int t = lane; t < 72; t += 64) z2[t] = zi;
    }
    LDS_FENCE();

    // ---- phase 0b: load 28x28 input into padded interior ----
    if (act) {
        const float4* xv = (const float4*)(x + (size_t)img * 784);
        for (int t = lane; t < 196; t += 64) {
            float4 v = xv[t];
            int row = t / 7;
            int c   = (t - row * 7) * 4;
            float* dst = in_p + (row + 1) * P_IN + c + 1;
            dst[0] = v.x; dst[1] = v.y; dst[2] = v.z; dst[3] = v.w;
        }
    }
    LDS_FENCE();

    // ---- phase 1: conv1 fp32 (+fp64 rescue) + pool-then-quant ----
    if (act) {
        #pragma unroll 1
        for (int it = 0; it < 3; ++it) {
            const int t = lane + (it << 6);            // < 192
            const int i = t / 14, j = t - i * 14;
            const float* base = in_p + (2 * i) * P_IN + 2 * j;
            float d[4][4];
            #pragma unroll
            for (int r = 0; r < 4; ++r) {
                float2 a = *(const float2*)(base + r * P_IN);
                float2 b = *(const float2*)(base + r * P_IN + 2);
                d[r][0] = a.x; d[r][1] = a.y; d[r][2] = b.x; d[r][3] = b.y;
            }
            float rr[4];
            float dmax = 0.f;
            #pragma unroll
            for (int oc = 0; oc < 4; ++oc) {
                float a00 = 0.f, a01 = 0.f, a10 = 0.f, a11 = 0.f;
                #pragma unroll
                for (int r = 0; r < 3; ++r)
                    #pragma unroll
                    for (int c = 0; c < 3; ++c) {
                        float wv = w1[oc * 9 + r * 3 + c];
                        a00 = fmaf(wv, d[r][c],         a00);
                        a01 = fmaf(wv, d[r][c + 1],     a01);
                        a10 = fmaf(wv, d[r + 1][c],     a10);
                        a11 = fmaf(wv, d[r + 1][c + 1], a11);
                    }
                float mx = fmaxf(fmaxf(a00, a01), fmaxf(a10, a11));
                float cc = fminf(fmaxf(0.5f * mx, 0.f), 3.f);
                float rv = rintf(cc);
                rr[oc] = rv;
                dmax = fmaxf(dmax, fabsf(cc - rv));    // 0.5 - dist to boundary
            }
            if (dmax > 0.5f - TOL2) {                  // rare fp64 rescue
                double dd[4][4];
                #pragma unroll
                for (int r = 0; r < 4; ++r)
                    #pragma unroll
                    for (int c = 0; c < 4; ++c) dd[r][c] = (double)d[r][c];
                #pragma unroll
                for (int oc = 0; oc < 4; ++oc) {
                    double a00 = 0, a01 = 0, a10 = 0, a11 = 0;
                    #pragma unroll
                    for (int r = 0; r < 3; ++r)
                        #pragma unroll
                        for (int c = 0; c < 3; ++c) {
                            double wv = (double)w1[oc * 9 + r * 3 + c];
                            a00 = fma(wv, dd[r][c],         a00);
                            a01 = fma(wv, dd[r][c + 1],     a01);
                            a10 = fma(wv, dd[r + 1][c],     a10);
                            a11 = fma(wv, dd[r + 1][c + 1], a11);
                        }
                    double mx = fmax(fmax(a00, a01), fmax(a10, a11));
                    rr[oc] = (float)rint(fmin(fmax(0.5 * mx, 0.0), 3.0));
                }
            }
            p1i[(i + 1) * P_P1 + (j + 1)] =
                (int)rr[0] | ((int)rr[1] << 8) | ((int)rr[2] << 16) | ((int)rr[3] << 24);
        }
        // tail: pixels 192..195, oc-split over lanes 0..15
        if (lane < 16) {
            const int px = 192 + (lane >> 2), oc = lane & 3;
            const int i = 13, j = px - 182;            // j in 10..13
            const float* base = in_p + (2 * i) * P_IN + 2 * j;
            float d[4][4];
            #pragma unroll
            for (int r = 0; r < 4; ++r) {
                float2 a = *(const float2*)(base + r * P_IN);
                float2 b = *(const float2*)(base + r * P_IN + 2);
                d[r][0] = a.x; d[r][1] = a.y; d[r][2] = b.x; d[r][3] = b.y;
            }
            const float* w9 = w1 + oc * 9;
            float a00 = 0.f, a01 = 0.f, a10 = 0.f, a11 = 0.f;
            #pragma unroll
            for (int r = 0; r < 3; ++r)
                #pragma unroll
                for (int c = 0; c < 3; ++c) {
                    float wv = w9[r * 3 + c];
                    a00 = fmaf(wv, d[r][c],         a00);
                    a01 = fmaf(wv, d[r][c + 1],     a01);
                    a10 = fmaf(wv, d[r + 1][c],     a10);
                    a11 = fmaf(wv, d[r + 1][c + 1], a11);
                }
            float mx = fmaxf(fmaxf(a00, a01), fmaxf(a10, a11));
            float cc = fminf(fmaxf(0.5f * mx, 0.f), 3.f);
            float rv = rintf(cc);
            if (fabsf(cc - rv) > 0.5f - TOL2) {
                double dd00 = 0, dd01 = 0, dd10 = 0, dd11 = 0;
                #pragma unroll
                for (int r = 0; r < 3; ++r)
                    #pragma unroll
                    for (int c = 0; c < 3; ++c) {
                        double wv = (double)w9[r * 3 + c];
                        dd00 = fma(wv, (double)d[r][c],         dd00);
                        dd01 = fma(wv, (double)d[r][c + 1],     dd01);
                        dd10 = fma(wv, (double)d[r + 1][c],     dd10);
                        dd11 = fma(wv, (double)d[r + 1][c + 1], dd11);
                    }
                double mxd = fmax(fmax(dd00, dd01), fmax(dd10, dd11));
                rv = (float)rint(fmin(fmax(0.5 * mxd, 0.0), 3.0));
            }
            int lv = (int)rv;
            int v = lv | (__shfl_xor(lv, 1, 64) << 8);
            v |= (__shfl_xor(v, 2, 64) << 16);
            if ((lane & 3) == 0)
                p1i[(i + 1) * P_P1 + (j + 1)] = v;
        }
    }
    LDS_FENCE();

    // ---- phase 2: conv2 via sdot4, 49 lanes x all 4 oc, patch loaded once ----
    if (act && lane < 49) {
        const int i = lane / 7, j = lane - 7 * i;
        const int* bp = p1i + (2 * i) * P_P1 + 2 * j;
        int d[4][4];
        #pragma unroll
        for (int r = 0; r < 4; ++r) {
            int2 a = *(const int2*)(bp + r * P_P1);
            int2 b = *(const int2*)(bp + r * P_P1 + 2);
            d[r][0] = a.x; d[r][1] = a.y; d[r][2] = b.x; d[r][3] = b.y;
        }
        const int L1 = wsi[WSI_L1], L3 = wsi[WSI_L3], L5 = wsi[WSI_L5];
        int pk = 0;
        #pragma unroll
        for (int oc = 0; oc < 4; ++oc) {
            int a00 = 0, a01 = 0, a10 = 0, a11 = 0;
            #pragma unroll
            for (int r = 0; r < 3; ++r)
                #pragma unroll
                for (int c = 0; c < 3; ++c) {
                    int wv = wsi[WSI_W2P + oc * 9 + r * 3 + c];  // uniform -> SGPR
                    a00 = dot4(d[r][c],         wv, a00);
                    a01 = dot4(d[r][c + 1],     wv, a01);
                    a10 = dot4(d[r + 1][c],     wv, a10);
                    a11 = dot4(d[r + 1][c + 1], wv, a11);
                }
            int mx = max(max(a00, a01), max(a10, a11));
            int lv = (mx >= L1) + (mx >= L3) + (mx >= L5);
            pk |= lv << (8 * oc);
        }
        p2i[lane] = pk;
    }
    LDS_FENCE();

    // ---- phase 3: FC via sdot4 + packed-int16 butterfly (5 chains not 10) ----
    if (act) {
        int p[5] = {0, 0, 0, 0, 0};
        if (lane < 49) {
            int h4 = p2i[lane];
            const int* wr = wsi + WSI_WFP + lane * 12;
            int4 wa = *(const int4*)wr;
            int4 wb = *(const int4*)(wr + 4);
            int2 wc = *(const int2*)(wr + 8);
            int a0 = dot4(h4, wa.x, 0), a1 = dot4(h4, wa.y, 0);
            int a2 = dot4(h4, wa.z, 0), a3 = dot4(h4, wa.w, 0);
            int a4 = dot4(h4, wb.x, 0), a5 = dot4(h4, wb.y, 0);
            int a6 = dot4(h4, wb.z, 0), a7 = dot4(h4, wb.w, 0);
            int a8 = dot4(h4, wc.x, 0), a9 = dot4(h4, wc.y, 0);
            p[0] = (a0 << 16) | (a1 & 0xFFFF);
            p[1] = (a2 << 16) | (a3 & 0xFFFF);
            p[2] = (a4 << 16) | (a5 & 0xFFFF);
            p[3] = (a6 << 16) | (a7 & 0xFFFF);
            p[4] = (a8 << 16) | (a9 & 0xFFFF);
        }
        #pragma unroll
        for (int off = 32; off; off >>= 1) {
            #pragma unroll
            for (int k = 0; k < 5; ++k)
                p[k] = pk_add16(p[k], __shfl_xor(p[k], off, 64));
        }
        if (lane == 0) {
            const float sf2 = wsf[WSF_SF2];
            float2* op = (float2*)(out + (size_t)img * 10);
            #pragma unroll
            for (int k = 0; k < 5; ++k) {
                int hi = p[k] >> 16;                   // output 2k
                int lo = (int)(short)(p[k] & 0xFFFF);  // output 2k+1
                op[k] = make_float2(sf2 * (float)hi, sf2 * (float)lo);
            }
        }
    }
}

extern "C" void kernel_launch(void* const* d_in, const int* in_sizes, int n_in,
                              void* d_out, int out_size, void* d_ws, size_t ws_size,
                              hipStream_t stream) {
    const float* x  = (const float*)d_in[0];
    const float* w1 = (const float*)d_in[1];
    const float* w2 = (const float*)d_in[2];
    const float* wf = (const float*)d_in[3];
    float* wsf = (float*)d_ws;
    float* out = (float*)d_out;

    const int B = in_sizes[0] / 784;

    qweights_kernel<<<1, 64, 0, stream>>>(w1, w2, wf, wsf);
    fused_net_kernel<<<(B + WAVES - 1) / WAVES, 256, 0, stream>>>(x, wsf, out, B);
}

// Round 7
// 183.027 us; speedup vs baseline: 1.5868x; 1.0806x over previous
//
#include <hip/hip_runtime.h>

// Workspace layout: float region + int region (ints start at (int*)wsf + 64)
#define WSF_W1Q  0      // 36 floats: s1*lvl (exact)
#define WSF_SF2  36     // 2*sf
#define WSI_W2P  0      // 36 ints: conv2 packed ternary i8x4 (ic in bytes), [oc][tap]
#define WSI_L1   36     // conv2 integer thresholds on L = sum(lvl_in * w), lvl in {0..3}
#define WSI_L3   37
#define WSI_L5   38
#define WSI_WFP  40     // 49*12 ints: FC packed ternary i8x4, [pix][o] pitch 12; byte b = wf[o][b*49+pix]

#define TOL2 4e-5f      // rescue band half-width in f-units (f = mx/2)

typedef float v2f __attribute__((ext_vector_type(2)));

__device__ __forceinline__ int dot4(int a, int b, int c) {
    return __builtin_amdgcn_sdot4(a, b, c, false);
}
__device__ __forceinline__ int pk_add16(int a, int b) {
    int r;
    asm("v_pk_add_i16 %0, %1, %2" : "=v"(r) : "v"(a), "v"(b));
    return r;
}
// packed 2xfp32 FMA, weight pair in SGPRs (uniform): src0 is the 1 allowed SGPR
__device__ __forceinline__ v2f pk_fma_sv(v2f ws, v2f d, v2f acc) {
    v2f r;
    asm("v_pk_fma_f32 %0, %1, %2, %3" : "=v"(r) : "s"(ws), "v"(d), "v"(acc));
    return r;
}

// wave-local LDS drain (no cross-wave rendezvous needed: zero inter-wave sharing)
#define LDS_FENCE() asm volatile("s_waitcnt lgkmcnt(0)" ::: "memory")

// ---------------------------------------------------------------------------
// Pre-kernel: 2-bit weight quant (fp64 decisions) + integer packing. 256 thr.
// ---------------------------------------------------------------------------
__global__ void qweights_kernel(const float* __restrict__ w1,
                                const float* __restrict__ w2,
                                const float* __restrict__ wf,
                                float* __restrict__ wsf) {
    int* wsi = (int*)wsf + 64;
    __shared__ float red[256];
    const int tid = threadIdx.x;

    float m = 0.f;
    if (tid < 36) m = fabsf(w1[tid]);
    red[tid] = m; __syncthreads();
    for (int s = 128; s > 0; s >>= 1) { if (tid < s) red[tid] = fmaxf(red[tid], red[tid + s]); __syncthreads(); }
    const float s1 = red[0]; __syncthreads();

    m = 0.f;
    if (tid < 144) m = fabsf(w2[tid]);
    red[tid] = m; __syncthreads();
    for (int s = 128; s > 0; s >>= 1) { if (tid < s) red[tid] = fmaxf(red[tid], red[tid + s]); __syncthreads(); }
    const float s2 = red[0]; __syncthreads();

    m = 0.f;
    for (int i = tid; i < 1960; i += 256) m = fmaxf(m, fabsf(wf[i]));
    red[tid] = m; __syncthreads();
    for (int s = 128; s > 0; s >>= 1) { if (tid < s) red[tid] = fmaxf(red[tid], red[tid + s]); __syncthreads(); }
    const float sf = red[0];

    if (tid < 36) {
        double l = rint((double)w1[tid] / (double)s1);
        l = fmin(fmax(l, -1.0), 1.0);
        wsf[WSF_W1Q + tid] = (float)(l * (double)s1);
    }
    if (tid >= 64 && tid < 100) {
        int u = tid - 64;
        int oc = u / 9, tap = u % 9;
        int dy = tap / 3, dx = tap % 3;
        int v = 0;
        for (int ic = 0; ic < 4; ++ic) {
            double l = rint((double)w2[((oc * 4 + ic) * 3 + dy) * 3 + dx] / (double)s2);
            l = fmin(fmax(l, -1.0), 1.0);
            v |= ((int)l & 0xFF) << (8 * ic);
        }
        wsi[WSI_W2P + u] = v;
    }
    // FC pack [pix][o]: byte b = lvl(wf[o*196 + b*49 + pix]) -- matches p2 packing
    for (int u = tid; u < 49 * 12; u += 256) {
        int pix = u / 12, o = u - 12 * pix;
        int v = 0;
        if (o < 10) {
            for (int b = 0; b < 4; ++b) {
                double l = rint((double)wf[o * 196 + b * 49 + pix] / (double)sf);
                l = fmin(fmax(l, -1.0), 1.0);
                v |= ((int)l & 0xFF) << (8 * b);
            }
        }
        wsi[WSI_WFP + u] = v;
    }
    // conv2 thresholds via wave-0 ballot: pre-act = 2*s2*L, L in [0,108]
    if (tid < 64) {
        const int lane = tid;
        double xa = 2.0 * (double)s2 * (double)lane;
        double xb = 2.0 * (double)s2 * (double)(lane + 64);
        double la = rint(fmin(fmax(xa, 0.0), 6.0) * 0.5);
        double lb = rint(fmin(fmax(xb, 0.0), 6.0) * 0.5);
        unsigned long long b1a = __ballot(la >= 1.0), b1b = __ballot(lb >= 1.0);
        unsigned long long b3a = __ballot(la >= 2.0), b3b = __ballot(lb >= 2.0);
        unsigned long long b5a = __ballot(la >= 3.0), b5b = __ballot(lb >= 3.0);
        if (lane == 0) {
            int L1 = b1a ? __ffsll(b1a) - 1 : (b1b ? 64 + __ffsll(b1b) - 1 : 4096);
            int L3 = b3a ? __ffsll(b3a) - 1 : (b3b ? 64 + __ffsll(b3b) - 1 : 4096);
            int L5 = b5a ? __ffsll(b5a) - 1 : (b5b ? 64 + __ffsll(b5b) - 1 : 4096);
            wsi[WSI_L1] = L1; wsi[WSI_L3] = L3; wsi[WSI_L5] = L5;
            wsf[WSF_SF2] = 2.0f * sf;
        }
    }
}

// ---------------------------------------------------------------------------
// Fused net: one wave per image, 4 waves/block, no __syncthreads.
// ---------------------------------------------------------------------------
#define WAVES 4
#define P_IN 30
#define P_P1 18

__global__ __launch_bounds__(256, 8)
void fused_net_kernel(const float* __restrict__ x,
                      const float* __restrict__ wsf,
                      float* __restrict__ out, int B) {
    const int* wsi = (const int*)wsf + 64;

    __shared__ __align__(16) float s_in[WAVES][900];        // 30x30 padded
    __shared__ __align__(16) int   s_p1[WAVES][16 * P_P1];  // packed lvl{0..3} x4 ic
    __shared__ __align__(16) int   s_p2[WAVES][52];         // [pix] packed 4 oc levels

    const int tid  = threadIdx.x;
    const int wave = tid >> 6;
    const int lane = tid & 63;
    const int img  = blockIdx.x * WAVES + wave;
    const bool act = (img < B);

    float* in_p = s_in[wave];
    int*   p1i  = s_p1[wave];
    int*   p2i  = s_p2[wave];
    const float* w1 = wsf + WSF_W1Q;

    // ---- phase 0a: zero exactly the READ-SET border frames ----
    // in_p: read set rows 0..29 x cols 0..29; interior rows/cols 1..28 written.
    if (lane < 30) { in_p[lane] = 0.f; in_p[29 * 30 + lane] = 0.f; }
    if (lane < 28) { in_p[(lane + 1) * 30] = 0.f; in_p[(lane + 1) * 30 + 29] = 0.f; }
    // p1i: read set rows 0..15 x cols 0..15; conv1 writes rows/cols 1..14 only.
    // Zero frame = rows {0,15} x cols 0..15  +  cols {0,15} x rows 1..14 = 60 cells.
    if (lane < 60) {
        int bi;
        if (lane < 16)      bi = lane;                       // row 0, cols 0..15
        else if (lane < 32) bi = 15 * P_P1 + (lane - 16);    // row 15, cols 0..15
        else if (lane < 46) bi = (lane - 31) * P_P1;         // rows 1..14, col 0
        else                bi = (lane - 45) * P_P1 + 15;    // rows 1..14, col 15
        p1i[bi] = 0;
    }

    // ---- phase 0b: load 28x28 input into padded interior ----
    if (act) {
        const float4* xv = (const float4*)(x + (size_t)img * 784);
        for (int t = lane; t < 196; t += 64) {
            float4 v = xv[t];
            int row = t / 7;
            int c   = (t - row * 7) * 4;
            float* dst = in_p + (row + 1) * P_IN + c + 1;
            dst[0] = v.x; dst[1] = v.y; dst[2] = v.z; dst[3] = v.w;
        }
    }
    LDS_FENCE();

    // ---- phase 1: conv1 via v_pk_fma_f32 (+fp64 rescue) + pool-then-quant ----
    if (act) {
        #pragma unroll 1
        for (int it = 0; it < 3; ++it) {
            const int t = lane + (it << 6);            // < 192
            const int i = t / 14, j = t - i * 14;
            const float* base = in_p + (2 * i) * P_IN + 2 * j;
            v2f A[4], S[4], Bp[4];                      // cols {0,1},{1,2},{2,3}
            #pragma unroll
            for (int r = 0; r < 4; ++r) {
                const float* rp = base + r * P_IN;
                A[r]  = *(const v2f*)rp;
                Bp[r] = *(const v2f*)(rp + 2);
                v2f s; s.x = rp[1]; s.y = rp[2];
                S[r] = s;
            }
            float rr[4];
            float dmax = 0.f;
            #pragma unroll
            for (int oc = 0; oc < 4; ++oc) {
                const float* w9 = w1 + oc * 9;
                v2f acc01 = {0.f, 0.f}, acc23 = {0.f, 0.f};
                #pragma unroll
                for (int r = 0; r < 3; ++r) {
                    float wa = w9[r * 3], wb = w9[r * 3 + 1], wc = w9[r * 3 + 2];
                    v2f wav = {wa, wa}, wbv = {wb, wb}, wcv = {wc, wc};
                    acc01 = pk_fma_sv(wav, A[r],      acc01);
                    acc01 = pk_fma_sv(wbv, S[r],      acc01);
                    acc01 = pk_fma_sv(wcv, Bp[r],     acc01);
                    acc23 = pk_fma_sv(wav, A[r + 1],  acc23);
                    acc23 = pk_fma_sv(wbv, S[r + 1],  acc23);
                    acc23 = pk_fma_sv(wcv, Bp[r + 1], acc23);
                }
                float mx = fmaxf(fmaxf(acc01.x, acc01.y), fmaxf(acc23.x, acc23.y));
                float cc = fminf(fmaxf(0.5f * mx, 0.f), 3.f);
                float rv = rintf(cc);
                rr[oc] = rv;
                dmax = fmaxf(dmax, fabsf(cc - rv));
            }
            if (dmax > 0.5f - TOL2) {                  // rare fp64 rescue
                double dd[4][4];
                #pragma unroll
                for (int r = 0; r < 4; ++r) {
                    dd[r][0] = (double)A[r].x; dd[r][1] = (double)A[r].y;
                    dd[r][2] = (double)Bp[r].x; dd[r][3] = (double)Bp[r].y;
                }
                #pragma unroll
                for (int oc = 0; oc < 4; ++oc) {
                    double a00 = 0, a01 = 0, a10 = 0, a11 = 0;
                    #pragma unroll
                    for (int r = 0; r < 3; ++r)
                        #pragma unroll
                        for (int c = 0; c < 3; ++c) {
                            double wv = (double)w1[oc * 9 + r * 3 + c];
                            a00 = fma(wv, dd[r][c],         a00);
                            a01 = fma(wv, dd[r][c + 1],     a01);
                            a10 = fma(wv, dd[r + 1][c],     a10);
                            a11 = fma(wv, dd[r + 1][c + 1], a11);
                        }
                    double mx = fmax(fmax(a00, a01), fmax(a10, a11));
                    rr[oc] = (float)rint(fmin(fmax(0.5 * mx, 0.0), 3.0));
                }
            }
            p1i[(i + 1) * P_P1 + (j + 1)] =
                (int)rr[0] | ((int)rr[1] << 8) | ((int)rr[2] << 16) | ((int)rr[3] << 24);
        }
        // tail: pixels 192..195, oc-split over lanes 0..15
        if (lane < 16) {
            const int px = 192 + (lane >> 2), oc = lane & 3;
            const int i = 13, j = px - 182;            // j in 10..13
            const float* base = in_p + (2 * i) * P_IN + 2 * j;
            float d[4][4];
            #pragma unroll
            for (int r = 0; r < 4; ++r) {
                float2 a = *(const float2*)(base + r * P_IN);
                float2 b = *(const float2*)(base + r * P_IN + 2);
                d[r][0] = a.x; d[r][1] = a.y; d[r][2] = b.x; d[r][3] = b.y;
            }
            const float* w9 = w1 + oc * 9;
            float a00 = 0.f, a01 = 0.f, a10 = 0.f, a11 = 0.f;
            #pragma unroll
            for (int r = 0; r < 3; ++r)
                #pragma unroll
                for (int c = 0; c < 3; ++c) {
                    float wv = w9[r * 3 + c];
                    a00 = fmaf(wv, d[r][c],         a00);
                    a01 = fmaf(wv, d[r][c + 1],     a01);
                    a10 = fmaf(wv, d[r + 1][c],     a10);
                    a11 = fmaf(wv, d[r + 1][c + 1], a11);
                }
            float mx = fmaxf(fmaxf(a00, a01), fmaxf(a10, a11));
            float cc = fminf(fmaxf(0.5f * mx, 0.f), 3.f);
            float rv = rintf(cc);
            if (fabsf(cc - rv) > 0.5f - TOL2) {
                double dd00 = 0, dd01 = 0, dd10 = 0, dd11 = 0;
                #pragma unroll
                for (int r = 0; r < 3; ++r)
                    #pragma unroll
                    for (int c = 0; c < 3; ++c) {
                        double wv = (double)w9[r * 3 + c];
                        dd00 = fma(wv, (double)d[r][c],         dd00);
                        dd01 = fma(wv, (double)d[r][c + 1],     dd01);
                        dd10 = fma(wv, (double)d[r + 1][c],     dd10);
                        dd11 = fma(wv, (double)d[r + 1][c + 1], dd11);
                    }
                double mxd = fmax(fmax(dd00, dd01), fmax(dd10, dd11));
                rv = (float)rint(fmin(fmax(0.5 * mxd, 0.0), 3.0));
            }
            int lv = (int)rv;
            int v = lv | (__shfl_xor(lv, 1, 64) << 8);
            v |= (__shfl_xor(v, 2, 64) << 16);
            if ((lane & 3) == 0)
                p1i[(i + 1) * P_P1 + (j + 1)] = v;
        }
    }
    LDS_FENCE();

    // ---- phase 2: conv2 via sdot4, 49 lanes x all 4 oc, patch loaded once ----
    if (act && lane < 49) {
        const int i = lane / 7, j = lane - 7 * i;
        const int* bp = p1i + (2 * i) * P_P1 + 2 * j;
        int d[4][4];
        #pragma unroll
        for (int r = 0; r < 4; ++r) {
            int2 a = *(const int2*)(bp + r * P_P1);
            int2 b = *(const int2*)(bp + r * P_P1 + 2);
            d[r][0] = a.x; d[r][1] = a.y; d[r][2] = b.x; d[r][3] = b.y;
        }
        const int L1 = wsi[WSI_L1], L3 = wsi[WSI_L3], L5 = wsi[WSI_L5];
        int pk = 0;
        #pragma unroll
        for (int oc = 0; oc < 4; ++oc) {
            int a00 = 0, a01 = 0, a10 = 0, a11 = 0;
            #pragma unroll
            for (int r = 0; r < 3; ++r)
                #pragma unroll
                for (int c = 0; c < 3; ++c) {
                    int wv = wsi[WSI_W2P + oc * 9 + r * 3 + c];  // uniform -> SGPR
                    a00 = dot4(d[r][c],         wv, a00);
                    a01 = dot4(d[r][c + 1],     wv, a01);
                    a10 = dot4(d[r + 1][c],     wv, a10);
                    a11 = dot4(d[r + 1][c + 1], wv, a11);
                }
            int mx = max(max(a00, a01), max(a10, a11));
            int lv = (mx >= L1) + (mx >= L3) + (mx >= L5);
            pk |= lv << (8 * oc);
        }
        p2i[lane] = pk;
    }
    LDS_FENCE();

    // ---- phase 3: FC via sdot4 + packed-int16 butterfly ----
    if (act) {
        int p[5] = {0, 0, 0, 0, 0};
        if (lane < 49) {
            int h4 = p2i[lane];
            const int* wr = wsi + WSI_WFP + lane * 12;
            int4 wa = *(const int4*)wr;
            int4 wb = *(const int4*)(wr + 4);
            int2 wc = *(const int2*)(wr + 8);
            int a0 = dot4(h4, wa.x, 0), a1 = dot4(h4, wa.y, 0);
            int a2 = dot4(h4, wa.z, 0), a3 = dot4(h4, wa.w, 0);
            int a4 = dot4(h4, wb.x, 0), a5 = dot4(h4, wb.y, 0);
            int a6 = dot4(h4, wb.z, 0), a7 = dot4(h4, wb.w, 0);
            int a8 = dot4(h4, wc.x, 0), a9 = dot4(h4, wc.y, 0);
            p[0] = (a0 << 16) | (a1 & 0xFFFF);
            p[1] = (a2 << 16) | (a3 & 0xFFFF);
            p[2] = (a4 << 16) | (a5 & 0xFFFF);
            p[3] = (a6 << 16) | (a7 & 0xFFFF);
            p[4] = (a8 << 16) | (a9 & 0xFFFF);
        }
        #pragma unroll
        for (int off = 32; off; off >>= 1) {
            #pragma unroll
            for (int k = 0; k < 5; ++k)
                p[k] = pk_add16(p[k], __shfl_xor(p[k], off, 64));
        }
        if (lane == 0) {
            const float sf2 = wsf[WSF_SF2];
            float2* op = (float2*)(out + (size_t)img * 10);
            #pragma unroll
            for (int k = 0; k < 5; ++k) {
                int hi = p[k] >> 16;
                int lo = (int)(short)(p[k] & 0xFFFF);
                op[k] = make_float2(sf2 * (float)hi, sf2 * (float)lo);
            }
        }
    }
}

extern "C" void kernel_launch(void* const* d_in, const int* in_sizes, int n_in,
                              void* d_out, int out_size, void* d_ws, size_t ws_size,
                              hipStream_t stream) {
    const float* x  = (const float*)d_in[0];
    const float* w1 = (const float*)d_in[1];
    const float* w2 = (const float*)d_in[2];
    const float* wf = (const float*)d_in[3];
    float* wsf = (float*)d_ws;
    float* out = (float*)d_out;

    const int B = in_sizes[0] / 784;

    qweights_kernel<<<1, 256, 0, stream>>>(w1, w2, wf, wsf);
    fused_net_kernel<<<(B + WAVES - 1) / WAVES, 256, 0, stream>>>(x, wsf, out, B);
}